// Round 3
// baseline (518.874 us; speedup 1.0000x reference)
//
#include <hip/hip_runtime.h>
#include <stdint.h>

// PositionLinearAttention on MI355X. B=8, C=256, Cqk=32, N=16384.
// Inputs fp32 (confirmed: reading them as bf16 NaN'd in R1), output fp32
// (confirmed: bf16-packed output in R2 gave error > max|ref| => layout garbage).
// Input reader still runtime-detected (bf16 vs fp32) as a safety net.
//
// Reformulation (V never materialized):
//   S[b][m][c']   = sum_n Kn[b][m][n] * x[b][c'][n]
//   x_sum[b][c']  = sum_n x[b][c'][n]
//   ksraw[b][m]   = sum_n Kn[b][m][n]
//   matrix[b][m][c] = sum_c' Wv[c][c'] S[b][m][c'] + bv[c]*ksraw[b][m]
//   value_sum[b][c] = sum_c' Wv[c][c'] x_sum[b][c'] + N*bv[c]
//   tailor[n] = 1/(N + sum_m Qn[m][n]*(ksraw[m]+EPS))
//   out[b][c][n] = x + gamma * tailor[n] * (value_sum[c] + sum_m Qn[m][n]*matrix[m][c])

#define NB 8
#define NC 256
#define CQK 32
#define NPIX 16384
#define NTILE 64
#define TN 256
#define PARTF (CQK*NC + NC + CQK)   // 8480 floats per partial block
#define EPSV 1e-6f

typedef unsigned short bfraw;

__device__ __forceinline__ float bf2f(bfraw u) {
    union { uint32_t i; float f; } v; v.i = ((uint32_t)u) << 16; return v.f;
}
__device__ __forceinline__ void unpack8(uint4 raw, float* xv) {
    xv[0] = bf2f((bfraw)(raw.x & 0xffffu)); xv[1] = bf2f((bfraw)(raw.x >> 16));
    xv[2] = bf2f((bfraw)(raw.y & 0xffffu)); xv[3] = bf2f((bfraw)(raw.y >> 16));
    xv[4] = bf2f((bfraw)(raw.z & 0xffffu)); xv[5] = bf2f((bfraw)(raw.z >> 16));
    xv[6] = bf2f((bfraw)(raw.w & 0xffffu)); xv[7] = bf2f((bfraw)(raw.w >> 16));
}

// DT=0: bf16 input, DT=1: fp32 input
template<int DT> __device__ __forceinline__ float ldx(const void* p, size_t i) {
    if (DT) return ((const float*)p)[i];
    return bf2f(((const bfraw*)p)[i]);
}
template<int DT> __device__ __forceinline__ void ld8(const void* p, size_t i, float* o) {
    if (DT) {
        const float4* q = (const float4*)((const float*)p + i);
        float4 a = q[0], b = q[1];
        o[0]=a.x;o[1]=a.y;o[2]=a.z;o[3]=a.w;o[4]=b.x;o[5]=b.y;o[6]=b.z;o[7]=b.w;
    } else {
        uint4 raw = *(const uint4*)((const bfraw*)p + i);
        unpack8(raw, o);
    }
}

// ---- dtype detector -----------------------------------------------------------
// fp32 random data read as bf16: ~74% insane exponents (crazy high).
// bf16-rounded-fp32 (low halves zero): even u16 indices all zero.
// genuine bf16: neither. flag=1 => read as fp32.
__global__ __launch_bounds__(256) void detect_kernel(const bfraw* __restrict__ x,
                                                     int* __restrict__ flag) {
    __shared__ int cnt, ez;
    int tid = threadIdx.x;
    if (tid == 0) { cnt = 0; ez = 0; }
    __syncthreads();
    int crazy = 0, evenzero = 0;
    for (int i = tid; i < 2048; i += 256) {
        bfraw u = x[i];
        float v = bf2f(u);
        float a = fabsf(v);
        if (!(a <= 1e10f) || (v != 0.f && a < 1e-10f)) crazy++;
        if ((i & 1) == 0 && u == 0) evenzero++;
    }
    atomicAdd(&cnt, crazy);
    atomicAdd(&ez, evenzero);
    __syncthreads();
    if (tid == 0) flag[0] = (cnt > 64 || ez > 900) ? 1 : 0;
}

// ---- prep: Wk,Wq -> fp32 transposed [C][CQK]; biases fp32 ---------------------
template<int DT> __device__ __forceinline__ void prep_body(
    const void* Wq, const void* bq, const void* Wk, const void* bk,
    float* wqT, float* wkT, float* bqf, float* bkf) {
    int tid = threadIdx.x;
    for (int i = tid; i < CQK*NC; i += 256) {
        int m = i / NC, c = i % NC;
        wqT[c*CQK + m] = ldx<DT>(Wq, i);
        wkT[c*CQK + m] = ldx<DT>(Wk, i);
    }
    if (tid < CQK) { bqf[tid] = ldx<DT>(bq, tid); bkf[tid] = ldx<DT>(bk, tid); }
}
__global__ __launch_bounds__(256) void prep_kernel(
    const void* Wq, const void* bq, const void* Wk, const void* bk,
    float* wqT, float* wkT, float* bqf, float* bkf, const int* flag) {
    if (flag[0]) prep_body<1>(Wq, bq, Wk, bk, wqT, wkT, bqf, bkf);
    else         prep_body<0>(Wq, bq, Wk, bk, wqT, wkT, bqf, bkf);
}

// ---- pass 1: K-proj + normalize + partial S / x_sum / ksum --------------------
template<int DT> __device__ __forceinline__ void pass1_body(
    const void* __restrict__ x, const float* __restrict__ wkT,
    const float* __restrict__ bkf, float* __restrict__ partial, int PB,
    float (*kn_s)[36]) {
    int tid = threadIdx.x;
    int b = blockIdx.x / PB, j = blockIdx.x % PB;

    float sacc[CQK];
    #pragma unroll
    for (int m = 0; m < CQK; ++m) sacc[m] = 0.f;
    float xsacc = 0.f, ksacc = 0.f;

    const size_t xb_base = (size_t)b * NC * NPIX;

    for (int tile = j; tile < NTILE; tile += PB) {
        int n0 = tile * TN;

        // phase A: K[:, n] = Wk @ x[:, n] + bk for pixel n = n0+tid
        float q[CQK];
        #pragma unroll
        for (int m = 0; m < CQK; ++m) q[m] = bkf[m];
        const size_t pix = xb_base + n0 + tid;
        #pragma unroll 4
        for (int c = 0; c < NC; ++c) {
            float xv = ldx<DT>(x, pix + (size_t)c * NPIX);
            const float4* w = (const float4*)(wkT + c*CQK);
            #pragma unroll
            for (int m4 = 0; m4 < 8; ++m4) {
                float4 wv = w[m4];
                q[m4*4+0] += wv.x * xv; q[m4*4+1] += wv.y * xv;
                q[m4*4+2] += wv.z * xv; q[m4*4+3] += wv.w * xv;
            }
        }
        float ss = 0.f;
        #pragma unroll
        for (int m = 0; m < CQK; ++m) ss += q[m]*q[m];
        float inv = rsqrtf(ss);

        __syncthreads();
        #pragma unroll
        for (int m4 = 0; m4 < 8; ++m4) {
            float4 kv;
            kv.x = q[m4*4+0]*inv; kv.y = q[m4*4+1]*inv;
            kv.z = q[m4*4+2]*inv; kv.w = q[m4*4+3]*inv;
            *((float4*)&kn_s[tid][m4*4]) = kv;
        }
        __syncthreads();

        // phase B: S[m][c=tid] += sum_k kn[k][m] * x[tid][n0+k]
        const size_t rowbase = xb_base + (size_t)tid * NPIX + n0;
        for (int k0 = 0; k0 < TN; k0 += 8) {
            float xv[8]; ld8<DT>(x, rowbase + k0, xv);
            #pragma unroll
            for (int kk = 0; kk < 8; ++kk) {
                const float4* kr = (const float4*)&kn_s[k0+kk][0];
                float xvk = xv[kk];
                #pragma unroll
                for (int m4 = 0; m4 < 8; ++m4) {
                    float4 a = kr[m4];
                    sacc[m4*4+0] += a.x*xvk; sacc[m4*4+1] += a.y*xvk;
                    sacc[m4*4+2] += a.z*xvk; sacc[m4*4+3] += a.w*xvk;
                }
                xsacc += xvk;
            }
        }

        if (tid < CQK) {
            float s = 0.f;
            for (int t = 0; t < TN; ++t) s += kn_s[t][tid];
            ksacc += s;
        }
    }

    size_t base = (size_t)blockIdx.x * PARTF;
    #pragma unroll
    for (int m = 0; m < CQK; ++m) partial[base + m*NC + tid] = sacc[m];
    partial[base + CQK*NC + tid] = xsacc;
    if (tid < CQK) partial[base + CQK*NC + NC + tid] = ksacc;
}
__global__ __launch_bounds__(256) void pass1_kernel(
    const void* __restrict__ x, const float* __restrict__ wkT,
    const float* __restrict__ bkf, float* __restrict__ partial, int PB,
    const int* __restrict__ flag) {
    __shared__ __align__(16) float kn_s[TN][36];
    if (flag[0]) pass1_body<1>(x, wkT, bkf, partial, PB, kn_s);
    else         pass1_body<0>(x, wkT, bkf, partial, PB, kn_s);
}

// ---- pass 1.5: reduce partials; matrix^T, value_sum, k_sum --------------------
template<int DT> __device__ __forceinline__ float dot256(const void* Wv, int row,
                                                         const float* sh) {
    float r = 0.f;
    for (int c0 = 0; c0 < NC; c0 += 8) {
        float xv[8]; ld8<DT>(Wv, (size_t)row * NC + c0, xv);
        #pragma unroll
        for (int i = 0; i < 8; ++i) r += xv[i] * sh[c0+i];
    }
    return r;
}
template<int DT> __device__ __forceinline__ void pass15_body(
    const float* __restrict__ partial, const void* __restrict__ Wv,
    const void* __restrict__ bv, float* __restrict__ matT,
    float* __restrict__ vsum, float* __restrict__ ksum, int PB, float* sh) {
    int tid = threadIdx.x;
    int b = blockIdx.x / 33, m = blockIdx.x % 33;
    const float* pb_ = partial + (size_t)b * PB * PARTF;

    if (m < CQK) {
        float acc = 0.f;
        for (int p = 0; p < PB; ++p) acc += pb_[(size_t)p*PARTF + m*NC + tid];
        sh[tid] = acc;
        float ks = 0.f;
        for (int p = 0; p < PB; ++p) ks += pb_[(size_t)p*PARTF + CQK*NC + NC + m];
        __syncthreads();
        float r = dot256<DT>(Wv, tid, sh);
        matT[((size_t)b*NC + tid)*CQK + m] = r + ldx<DT>(bv, tid) * ks;
        if (tid == 0) ksum[b*CQK + m] = ks + EPSV;
    } else {
        float acc = 0.f;
        for (int p = 0; p < PB; ++p) acc += pb_[(size_t)p*PARTF + CQK*NC + tid];
        sh[tid] = acc;
        __syncthreads();
        float r = dot256<DT>(Wv, tid, sh);
        vsum[b*NC + tid] = r + (float)NPIX * ldx<DT>(bv, tid);
    }
}
__global__ __launch_bounds__(256) void pass15_kernel(
    const float* __restrict__ partial, const void* __restrict__ Wv,
    const void* __restrict__ bv, float* __restrict__ matT,
    float* __restrict__ vsum, float* __restrict__ ksum, int PB,
    const int* __restrict__ flag) {
    __shared__ float sh[NC];
    if (flag[0]) pass15_body<1>(partial, Wv, bv, matT, vsum, ksum, PB, sh);
    else         pass15_body<0>(partial, Wv, bv, matT, vsum, ksum, PB, sh);
}

// ---- pass 2: Q-proj + normalize + tailor + fp32 output ------------------------
template<int DT> __device__ __forceinline__ void pass2_body(
    const void* __restrict__ x, const float* __restrict__ wqT,
    const float* __restrict__ bqf, const float* __restrict__ ksum,
    const float* __restrict__ matT, const float* __restrict__ vsum,
    const void* __restrict__ gamma, float* __restrict__ out) {
    int tid = threadIdx.x;
    int b = blockIdx.x / NTILE, tile = blockIdx.x % NTILE;
    int n0 = tile * TN;
    const size_t xb_base = (size_t)b * NC * NPIX;
    const size_t pix = xb_base + n0 + tid;

    float q[CQK];
    #pragma unroll
    for (int m = 0; m < CQK; ++m) q[m] = bqf[m];
    #pragma unroll 4
    for (int c = 0; c < NC; ++c) {
        float xv = ldx<DT>(x, pix + (size_t)c * NPIX);
        const float4* w = (const float4*)(wqT + c*CQK);
        #pragma unroll
        for (int m4 = 0; m4 < 8; ++m4) {
            float4 wv = w[m4];
            q[m4*4+0] += wv.x * xv; q[m4*4+1] += wv.y * xv;
            q[m4*4+2] += wv.z * xv; q[m4*4+3] += wv.w * xv;
        }
    }
    float ss = 0.f;
    #pragma unroll
    for (int m = 0; m < CQK; ++m) ss += q[m]*q[m];
    float inv = rsqrtf(ss);
    const float* ksb = ksum + b*CQK;
    float dot = 0.f;
    #pragma unroll
    for (int m = 0; m < CQK; ++m) { q[m] *= inv; dot += q[m] * ksb[m]; }
    float tl = 1.f / ((float)NPIX + dot);
    float gt = ldx<DT>(gamma, 0) * tl;

    const float* mb = matT + (size_t)b*NC*CQK;
    const float* vb = vsum + (size_t)b*NC;
    float* op = out + pix;
    #pragma unroll 2
    for (int c = 0; c < NC; ++c) {
        float r = vb[c];
        const float4* mr = (const float4*)(mb + c*CQK);
        #pragma unroll
        for (int m4 = 0; m4 < 8; ++m4) {
            float4 a = mr[m4];
            r += q[m4*4+0]*a.x + q[m4*4+1]*a.y + q[m4*4+2]*a.z + q[m4*4+3]*a.w;
        }
        float xv = ldx<DT>(x, pix + (size_t)c * NPIX);
        op[(size_t)c * NPIX] = xv + gt*r;
    }
}
__global__ __launch_bounds__(256) void pass2_kernel(
    const void* __restrict__ x, const float* __restrict__ wqT,
    const float* __restrict__ bqf, const float* __restrict__ ksum,
    const float* __restrict__ matT, const float* __restrict__ vsum,
    const void* __restrict__ gamma, float* __restrict__ out,
    const int* __restrict__ flag) {
    if (flag[0]) pass2_body<1>(x, wqT, bqf, ksum, matT, vsum, gamma, out);
    else         pass2_body<0>(x, wqT, bqf, ksum, matT, vsum, gamma, out);
}

// ---- host ----------------------------------------------------------------------
extern "C" void kernel_launch(void* const* d_in, const int* in_sizes, int n_in,
                              void* d_out, int out_size, void* d_ws, size_t ws_size,
                              hipStream_t stream)
{
    const void* x  = d_in[0];
    const void* Wq = d_in[1];
    const void* bq = d_in[2];
    const void* Wk = d_in[3];
    const void* bk = d_in[4];
    const void* Wv = d_in[5];
    const void* bv = d_in[6];
    const void* gm = d_in[7];
    float* out = (float*)d_out;

    float* ws = (float*)d_ws;
    int*  flag = (int*)ws;              // 16 floats reserved
    float* wkT = ws + 16;               // 8192
    float* wqT = wkT + CQK*NC;          // 8192
    float* bkf = wqT + CQK*NC;          // 32
    float* bqf = bkf + CQK;             // 32
    float* matT = bqf + CQK;            // NB*NC*CQK = 65536
    float* vsum = matT + NB*NC*CQK;     // 2048
    float* ksum = vsum + NB*NC;         // 256
    float* partial = ksum + NB*CQK;

    size_t fixedf = (size_t)(partial - ws);
    int PB = 64;
    while (PB > 1 && (fixedf + (size_t)NB*PB*PARTF) * 4 > ws_size) PB >>= 1;

    hipLaunchKernelGGL(detect_kernel, dim3(1), dim3(256), 0, stream,
                       (const bfraw*)x, flag);
    hipLaunchKernelGGL(prep_kernel, dim3(1), dim3(256), 0, stream,
                       Wq, bq, Wk, bk, wqT, wkT, bqf, bkf, flag);
    hipLaunchKernelGGL(pass1_kernel, dim3(NB*PB), dim3(256), 0, stream,
                       x, wkT, bkf, partial, PB, flag);
    hipLaunchKernelGGL(pass15_kernel, dim3(NB*33), dim3(256), 0, stream,
                       partial, Wv, bv, matT, vsum, ksum, PB, flag);
    hipLaunchKernelGGL(pass2_kernel, dim3(NB*NTILE), dim3(256), 0, stream,
                       x, wqT, bqf, ksum, matT, vsum, gm, out, flag);
}

// Round 4
// 491.758 us; speedup vs baseline: 1.0551x; 1.0551x over previous
//
#include <hip/hip_runtime.h>
#include <stdint.h>

// PositionLinearAttention on MI355X. B=8, C=256, Cqk=32, N=16384.
// Inputs fp32 (runtime-detected reader as safety net), output fp32. R3 passed
// at 519 us; R4 restructure: Q-proj fused into pass1 (shared x read), pass2
// becomes a pure high-occupancy epilogue (c-split grid, 8 blocks/CU).
//
// Reformulation (V never materialized):
//   S[b][m][c']   = sum_n Kn[b][m][n] * x[b][c'][n]
//   matrix[b][m][c] = sum_c' Wv[c][c'] S[b][m][c'] + bv[c]*ksraw[b][m]
//   value_sum[b][c] = sum_c' Wv[c][c'] x_sum[b][c'] + N*bv[c]
//   tailor[n] = 1/(N + Qn[n]·(ksraw+EPS))
//   out[b][c][n] = x + gamma*tailor[n]*(value_sum[c] + Qn[n]·matrix[:,c])

#define NB 8
#define NC 256
#define CQK 32
#define NPIX 16384
#define NTILE 64
#define TN 256
#define PARTF (CQK*NC + NC + CQK)   // 8480 floats per partial block
#define EPSV 1e-6f

typedef unsigned short bfraw;

__device__ __forceinline__ float bf2f(bfraw u) {
    union { uint32_t i; float f; } v; v.i = ((uint32_t)u) << 16; return v.f;
}
__device__ __forceinline__ void unpack8(uint4 raw, float* xv) {
    xv[0] = bf2f((bfraw)(raw.x & 0xffffu)); xv[1] = bf2f((bfraw)(raw.x >> 16));
    xv[2] = bf2f((bfraw)(raw.y & 0xffffu)); xv[3] = bf2f((bfraw)(raw.y >> 16));
    xv[4] = bf2f((bfraw)(raw.z & 0xffffu)); xv[5] = bf2f((bfraw)(raw.z >> 16));
    xv[6] = bf2f((bfraw)(raw.w & 0xffffu)); xv[7] = bf2f((bfraw)(raw.w >> 16));
}
// DT=0: bf16 input, DT=1: fp32 input
template<int DT> __device__ __forceinline__ float ldx(const void* p, size_t i) {
    if (DT) return ((const float*)p)[i];
    return bf2f(((const bfraw*)p)[i]);
}
template<int DT> __device__ __forceinline__ void ld8(const void* p, size_t i, float* o) {
    if (DT) {
        const float4* q = (const float4*)((const float*)p + i);
        float4 a = q[0], b = q[1];
        o[0]=a.x;o[1]=a.y;o[2]=a.z;o[3]=a.w;o[4]=b.x;o[5]=b.y;o[6]=b.z;o[7]=b.w;
    } else {
        uint4 raw = *(const uint4*)((const bfraw*)p + i);
        unpack8(raw, o);
    }
}

// ---- detect dtype + prep weights (merged, 1 block) ----------------------------
// Fused weight layout wkqT[c][0..31]=Wk col c, [32..63]=Wq col c. bkq likewise.
template<int DT> __device__ __forceinline__ void prep_body(
    const void* Wq, const void* bq, const void* Wk, const void* bk,
    float* wkqT, float* bkq) {
    int tid = threadIdx.x;
    for (int i = tid; i < CQK*NC; i += 256) {
        int m = i >> 8, c = i & 255;
        wkqT[c*64 + m]      = ldx<DT>(Wk, i);
        wkqT[c*64 + 32 + m] = ldx<DT>(Wq, i);
    }
    if (tid < CQK)      bkq[tid]      = ldx<DT>(bk, tid);
    else if (tid < 64)  bkq[tid]      = ldx<DT>(bq, tid - 32);
}
__global__ __launch_bounds__(256) void detprep_kernel(
    const bfraw* __restrict__ xr, const void* Wq, const void* bq,
    const void* Wk, const void* bk,
    int* __restrict__ flag, float* __restrict__ wkqT, float* __restrict__ bkq) {
    __shared__ int cnt, ez, fl_s;
    int tid = threadIdx.x;
    if (tid == 0) { cnt = 0; ez = 0; }
    __syncthreads();
    int crazy = 0, evenzero = 0;
    for (int i = tid; i < 2048; i += 256) {
        bfraw u = xr[i];
        float v = bf2f(u);
        float a = fabsf(v);
        if (!(a <= 1e10f) || (v != 0.f && a < 1e-10f)) crazy++;
        if ((i & 1) == 0 && u == 0) evenzero++;
    }
    atomicAdd(&cnt, crazy);
    atomicAdd(&ez, evenzero);
    __syncthreads();
    if (tid == 0) { fl_s = (cnt > 64 || ez > 900) ? 1 : 0; flag[0] = fl_s; }
    __syncthreads();
    if (fl_s) prep_body<1>(Wq, bq, Wk, bk, wkqT, bkq);
    else      prep_body<0>(Wq, bq, Wk, bk, wkqT, bkq);
}

// ---- pass 1: K+Q proj, normalize; Qn -> global; partial S / x_sum / ksum ------
template<int DT> __device__ __forceinline__ void pass1_body(
    const void* __restrict__ x, const float* __restrict__ wkqT,
    const float* __restrict__ bkq, float4* __restrict__ qn4,
    float* __restrict__ partial, int PB, float (*kn_s)[36]) {
    int tid = threadIdx.x;
    int b = blockIdx.x / PB, j = blockIdx.x % PB;

    float sacc[CQK];
    #pragma unroll
    for (int m = 0; m < CQK; ++m) sacc[m] = 0.f;
    float xsacc = 0.f, ksacc = 0.f;

    const size_t xb_base = (size_t)b * NC * NPIX;

    for (int tile = j; tile < NTILE; tile += PB) {
        int n0 = tile * TN;

        // phase A: k|q[:, n] = W @ x[:, n] + b for pixel n = n0+tid
        float kq[64];
        #pragma unroll
        for (int m = 0; m < 64; ++m) kq[m] = bkq[m];
        const size_t pixi = xb_base + n0 + tid;
        for (int c0 = 0; c0 < NC; c0 += 8) {
            float xv[8];
            #pragma unroll
            for (int jj = 0; jj < 8; ++jj)
                xv[jj] = ldx<DT>(x, pixi + (size_t)(c0+jj) * NPIX);
            #pragma unroll
            for (int jj = 0; jj < 8; ++jj) {
                const float4* w = (const float4*)(wkqT + (c0+jj)*64); // uniform
                #pragma unroll
                for (int m4 = 0; m4 < 16; ++m4) {
                    float4 wv = w[m4];
                    kq[m4*4+0] += wv.x * xv[jj]; kq[m4*4+1] += wv.y * xv[jj];
                    kq[m4*4+2] += wv.z * xv[jj]; kq[m4*4+3] += wv.w * xv[jj];
                }
            }
        }
        float ssk = 0.f, ssq = 0.f;
        #pragma unroll
        for (int m = 0; m < CQK; ++m) {
            ssk += kq[m]*kq[m]; ssq += kq[32+m]*kq[32+m];
        }
        float invk = rsqrtf(ssk), invq = rsqrtf(ssq);

        __syncthreads();   // previous tile's kn_s readers done
        #pragma unroll
        for (int m4 = 0; m4 < 8; ++m4) {
            float4 kv;
            kv.x = kq[m4*4+0]*invk; kv.y = kq[m4*4+1]*invk;
            kv.z = kq[m4*4+2]*invk; kv.w = kq[m4*4+3]*invk;
            *((float4*)&kn_s[tid][m4*4]) = kv;
        }
        __syncthreads();

        // Qn -> global, coalesced [b][m4][n]
        float4* qp = qn4 + (size_t)b * 8 * NPIX + (n0 + tid);
        #pragma unroll
        for (int m4 = 0; m4 < 8; ++m4) {
            float4 qv;
            qv.x = kq[32+m4*4+0]*invq; qv.y = kq[32+m4*4+1]*invq;
            qv.z = kq[32+m4*4+2]*invq; qv.w = kq[32+m4*4+3]*invq;
            qp[(size_t)m4 * NPIX] = qv;
        }

        // phase B: S[m][c=tid] += sum_k kn[k][m] * x[tid][n0+k]
        const size_t rowbase = xb_base + (size_t)tid * NPIX + n0;
        for (int k0 = 0; k0 < TN; k0 += 8) {
            float xv[8]; ld8<DT>(x, rowbase + k0, xv);
            #pragma unroll
            for (int kk = 0; kk < 8; ++kk) {
                const float4* kr = (const float4*)&kn_s[k0+kk][0];
                float xvk = xv[kk];
                #pragma unroll
                for (int m4 = 0; m4 < 8; ++m4) {
                    float4 a = kr[m4];
                    sacc[m4*4+0] += a.x*xvk; sacc[m4*4+1] += a.y*xvk;
                    sacc[m4*4+2] += a.z*xvk; sacc[m4*4+3] += a.w*xvk;
                }
                xsacc += xvk;
            }
        }

        if (tid < CQK) {
            float s = 0.f;
            for (int t = 0; t < TN; ++t) s += kn_s[t][tid];
            ksacc += s;
        }
    }

    size_t base = (size_t)blockIdx.x * PARTF;
    #pragma unroll
    for (int m = 0; m < CQK; ++m) partial[base + m*NC + tid] = sacc[m];
    partial[base + CQK*NC + tid] = xsacc;
    if (tid < CQK) partial[base + CQK*NC + NC + tid] = ksacc;
}
__global__ __launch_bounds__(256) void pass1_kernel(
    const void* __restrict__ x, const float* __restrict__ wkqT,
    const float* __restrict__ bkq, float4* __restrict__ qn4,
    float* __restrict__ partial, int PB, const int* __restrict__ flag) {
    __shared__ __align__(16) float kn_s[TN][36];
    if (flag[0]) pass1_body<1>(x, wkqT, bkq, qn4, partial, PB, kn_s);
    else         pass1_body<0>(x, wkqT, bkq, qn4, partial, PB, kn_s);
}

// ---- pass 1.5: reduce partials; matrix^T [b][c][32], value_sum, k_sum ---------
template<int DT> __device__ __forceinline__ float dot256(const void* Wv, int row,
                                                         const float* sh) {
    float r = 0.f;
    for (int c0 = 0; c0 < NC; c0 += 8) {
        float xv[8]; ld8<DT>(Wv, (size_t)row * NC + c0, xv);
        #pragma unroll
        for (int i = 0; i < 8; ++i) r += xv[i] * sh[c0+i];
    }
    return r;
}
template<int DT> __device__ __forceinline__ void pass15_body(
    const float* __restrict__ partial, const void* __restrict__ Wv,
    const void* __restrict__ bv, float* __restrict__ matT,
    float* __restrict__ vsum, float* __restrict__ ksum, int PB, float* sh) {
    int tid = threadIdx.x;
    int b = blockIdx.x / 33, m = blockIdx.x % 33;
    const float* pb_ = partial + (size_t)b * PB * PARTF;

    if (m < CQK) {
        float acc = 0.f;
        for (int p = 0; p < PB; ++p) acc += pb_[(size_t)p*PARTF + m*NC + tid];
        sh[tid] = acc;
        float ks = 0.f;
        for (int p = 0; p < PB; ++p) ks += pb_[(size_t)p*PARTF + CQK*NC + NC + m];
        __syncthreads();
        float r = dot256<DT>(Wv, tid, sh);
        matT[((size_t)b*NC + tid)*CQK + m] = r + ldx<DT>(bv, tid) * ks;
        if (tid == 0) ksum[b*CQK + m] = ks + EPSV;
    } else {
        float acc = 0.f;
        for (int p = 0; p < PB; ++p) acc += pb_[(size_t)p*PARTF + CQK*NC + tid];
        sh[tid] = acc;
        __syncthreads();
        float r = dot256<DT>(Wv, tid, sh);
        vsum[b*NC + tid] = r + (float)NPIX * ldx<DT>(bv, tid);
    }
}
__global__ __launch_bounds__(256) void pass15_kernel(
    const float* __restrict__ partial, const void* __restrict__ Wv,
    const void* __restrict__ bv, float* __restrict__ matT,
    float* __restrict__ vsum, float* __restrict__ ksum, int PB,
    const int* __restrict__ flag) {
    __shared__ float sh[NC];
    if (flag[0]) pass15_body<1>(partial, Wv, bv, matT, vsum, ksum, PB, sh);
    else         pass15_body<0>(partial, Wv, bv, matT, vsum, ksum, PB, sh);
}

// ---- pass 2: epilogue. grid = NB*64*4 (b, pixel-tile, c-chunk of 64) ----------
template<int DT> __device__ __forceinline__ void pass2_body(
    const void* __restrict__ x, const float4* __restrict__ qn4,
    const float* __restrict__ ksum, const float* __restrict__ matT,
    const float* __restrict__ vsum, const void* __restrict__ gamma,
    float* __restrict__ out) {
    int tid = threadIdx.x;
    int bx = blockIdx.x;
    int cs = bx & 3, tile = (bx >> 2) & 63, b = bx >> 8;
    int n0 = tile * TN;
    int p = n0 + tid;

    float q[CQK];
    const float4* qp = qn4 + (size_t)b * 8 * NPIX + p;
    #pragma unroll
    for (int m4 = 0; m4 < 8; ++m4) {
        float4 v = qp[(size_t)m4 * NPIX];
        q[m4*4+0]=v.x; q[m4*4+1]=v.y; q[m4*4+2]=v.z; q[m4*4+3]=v.w;
    }
    const float* ksb = ksum + b*CQK;   // uniform
    float dot = 0.f;
    #pragma unroll
    for (int m = 0; m < CQK; ++m) dot += q[m] * ksb[m];
    float tl = 1.f / ((float)NPIX + dot);
    float gt = ldx<DT>(gamma, 0) * tl;

    int c0 = cs * 64;
    const float* mb = matT + ((size_t)b*NC + c0)*CQK;  // uniform rows
    const float* vb = vsum + (size_t)b*NC + c0;
    size_t xbase = (size_t)b*NC*NPIX + (size_t)c0*NPIX + p;

    for (int ci = 0; ci < 64; ci += 4) {
        float xv[4];
        #pragma unroll
        for (int u = 0; u < 4; ++u)
            xv[u] = ldx<DT>(x, xbase + (size_t)(ci+u)*NPIX);
        #pragma unroll
        for (int u = 0; u < 4; ++u) {
            float r = vb[ci+u];
            const float4* mr = (const float4*)(mb + (ci+u)*CQK);  // uniform
            #pragma unroll
            for (int m4 = 0; m4 < 8; ++m4) {
                float4 a = mr[m4];
                r += q[m4*4+0]*a.x + q[m4*4+1]*a.y + q[m4*4+2]*a.z + q[m4*4+3]*a.w;
            }
            out[xbase + (size_t)(ci+u)*NPIX] = xv[u] + gt*r;
        }
    }
}
__global__ __launch_bounds__(256) void pass2_kernel(
    const void* __restrict__ x, const float4* __restrict__ qn4,
    const float* __restrict__ ksum, const float* __restrict__ matT,
    const float* __restrict__ vsum, const void* __restrict__ gamma,
    float* __restrict__ out, const int* __restrict__ flag) {
    if (flag[0]) pass2_body<1>(x, qn4, ksum, matT, vsum, gamma, out);
    else         pass2_body<0>(x, qn4, ksum, matT, vsum, gamma, out);
}

// ---- host ----------------------------------------------------------------------
extern "C" void kernel_launch(void* const* d_in, const int* in_sizes, int n_in,
                              void* d_out, int out_size, void* d_ws, size_t ws_size,
                              hipStream_t stream)
{
    const void* x  = d_in[0];
    const void* Wq = d_in[1];
    const void* bq = d_in[2];
    const void* Wk = d_in[3];
    const void* bk = d_in[4];
    const void* Wv = d_in[5];
    const void* bv = d_in[6];
    const void* gm = d_in[7];
    float* out = (float*)d_out;

    float* ws = (float*)d_ws;
    int*   flag = (int*)ws;             // 16 floats reserved
    float* wkqT = ws + 16;              // 16384
    float* bkq  = wkqT + 64*NC;         // 64
    float* matT = bkq + 64;             // NB*NC*CQK = 65536
    float* vsum = matT + NB*NC*CQK;     // 2048
    float* ksum = vsum + NB*NC;         // 256
    float* qn4f = ksum + NB*CQK;        // NB*8*NPIX*4 = 4194304 (16B-aligned)
    float* partial = qn4f + (size_t)NB*8*NPIX*4;

    size_t fixedf = (size_t)(partial - ws);
    int PB = 64;
    while (PB > 1 && (fixedf + (size_t)NB*PB*PARTF) * 4 > ws_size) PB >>= 1;

    hipLaunchKernelGGL(detprep_kernel, dim3(1), dim3(256), 0, stream,
                       (const bfraw*)x, Wq, bq, Wk, bk, flag, wkqT, bkq);
    hipLaunchKernelGGL(pass1_kernel, dim3(NB*PB), dim3(256), 0, stream,
                       x, wkqT, bkq, (float4*)qn4f, partial, PB, flag);
    hipLaunchKernelGGL(pass15_kernel, dim3(NB*33), dim3(256), 0, stream,
                       partial, Wv, bv, matT, vsum, ksum, PB, flag);
    hipLaunchKernelGGL(pass2_kernel, dim3(NB*NTILE*4), dim3(256), 0, stream,
                       x, (const float4*)qn4f, ksum, matT, vsum, gm, out, flag);
}